// Round 7
// baseline (312.069 us; speedup 1.0000x reference)
//
#include <hip/hip_runtime.h>
#include <hip/hip_bf16.h>
#include <math.h>

// Problem constants (from reference)
#define B       64
#define S_VIT   257
#define S_Q     32
#define L       512
#define IMG     1408
#define HID     768
#define C       30000
#define H_CLUB  32
#define H_MINE  64

// ---------------------------------------------------------------------------
// Workspace layout (float offsets). Zeroed region = [0, WS_ZERO_FLOATS).
//   xv_sum : B*IMG  fp32 (atomic sum over S_VIT; /257 at use)
//   y_hist : B*C    fp32 (counts; /512 at use; exact ints, order-independent)
//   dv64/dq64 : B*H_MINE fp64 (atomic fp64 accumulation)
//   ctr    : 1 uint ticket counter
//   xq     : B*HID fp32  (outside zero region; fully written)
//   club_partial : 64 fp64 (one per b; fully written before ticket-gated read)
// Precision ledger (absmax == 2.980232e-08 == 1 ulp of out, threshold 1.08 ulp):
//   - per-(b,c) fp32 term expression FROZEN since round 3.
//   - fp64 summation ORDER is free (R4->R6 reorders left absmax bit-identical).
//   - sparse skip of y==yp==0 terms adds exact zeros only (dn==dp -> 0 in fp32).
// ---------------------------------------------------------------------------
#define OFF_XVSUM   0
#define OFF_YHIST   (OFF_XVSUM + B * IMG)            // 90112
#define OFF_DV64    (OFF_YHIST + B * C)              // 2010112 (byte 8040448, 8-aligned)
#define OFF_DQ64    (OFF_DV64 + 2 * B * H_MINE)      // 2018304
#define OFF_CTR     (OFF_DQ64 + 2 * B * H_MINE)      // 2026496
#define WS_ZERO_FLOATS (OFF_CTR + 4)                 // 2026500
#define OFF_XQ      WS_ZERO_FLOATS                   // 2026500 (byte 8106000, 16-aligned)
#define OFF_CLUBP   (OFF_XQ + B * HID)               // 2075652 (byte 8302608, 8-aligned)

#define N_BC_BLOCKS (256 + B)                        // 320: MINE(256) + CLUB(64)

// ---------------------------------------------------------------------------
// K_A: vit mean, 16 splits (blocks 0..1023) + xq mean float4 (1024..1071)
//      + label histogram (1072..1079).
// ---------------------------------------------------------------------------
__global__ void k_stage_a(const float* __restrict__ vit, const float* __restrict__ qf,
                          const int* __restrict__ label,
                          float* __restrict__ xv_sum, float* __restrict__ xq,
                          float* __restrict__ y_hist) {
    const int blk = blockIdx.x;
    const int tid = threadIdx.x;
    if (blk < 1024) {
        const int b     = blk >> 4;
        const int split = blk & 15;
        const int s0 = (split * S_VIT) >> 4;
        const int s1 = ((split + 1) * S_VIT) >> 4;
        const float4* row = (const float4*)(vit + (size_t)b * S_VIT * IMG);
        float4 a0 = make_float4(0.f, 0.f, 0.f, 0.f);
        float4 a1 = make_float4(0.f, 0.f, 0.f, 0.f);
        const bool second = (tid < 96);  // 352 float4 columns; 256 + 96
        for (int s = s0; s < s1; ++s) {
            const float4* p = row + (size_t)s * (IMG / 4);
            float4 v = p[tid];
            a0.x += v.x; a0.y += v.y; a0.z += v.z; a0.w += v.w;
            if (second) {
                float4 w = p[tid + 256];
                a1.x += w.x; a1.y += w.y; a1.z += w.z; a1.w += w.w;
            }
        }
        float* out = xv_sum + (size_t)b * IMG;
        atomicAdd(&out[tid * 4 + 0], a0.x);
        atomicAdd(&out[tid * 4 + 1], a0.y);
        atomicAdd(&out[tid * 4 + 2], a0.z);
        atomicAdd(&out[tid * 4 + 3], a0.w);
        if (second) {
            atomicAdd(&out[(tid + 256) * 4 + 0], a1.x);
            atomicAdd(&out[(tid + 256) * 4 + 1], a1.y);
            atomicAdd(&out[(tid + 256) * 4 + 2], a1.z);
            atomicAdd(&out[(tid + 256) * 4 + 3], a1.w);
        }
    } else if (blk < 1072) {
        const int idx = (blk - 1024) * 256 + tid;      // < B*HID/4
        const int b  = idx / (HID / 4);
        const int k4 = idx % (HID / 4);
        const float* base = qf + (size_t)b * S_Q * HID + k4 * 4;
        float4 s = make_float4(0.f, 0.f, 0.f, 0.f);
        #pragma unroll
        for (int t = 0; t < S_Q; ++t) {
            const float4 v = *(const float4*)(base + (size_t)t * HID);
            s.x += v.x; s.y += v.y; s.z += v.z; s.w += v.w;
        }
        const float inv = 1.0f / (float)S_Q;
        s.x *= inv; s.y *= inv; s.z *= inv; s.w *= inv;
        ((float4*)xq)[(size_t)b * (HID / 4) + k4] = s;
    } else {
        const int idx = (blk - 1072) * 256 + tid;      // 0..2047
        for (int t = idx; t < B * L; t += 2048) {
            int lab = label[t];
            if (lab == -100) lab = 0;
            const int b = t >> 9;                      // t / L
            atomicAdd(&y_hist[(size_t)b * C + lab], 1.0f);
        }
    }
}

// ---------------------------------------------------------------------------
// K_BC: MINE dots (blocks 0..255) + CLUB hidden+SPARSE main per-b (256..319)
//       + ticket-fused final (last-finishing block).
// Sparse CLUB: only c in labels[b] ∪ labels[perm[b]] can have y!=0 or yp!=0;
// all other terms are exactly 0 (dn==dp). LDS hash dedups the <=1024
// candidates; per-distinct-c term math is bit-identical to the dense kernel.
// ---------------------------------------------------------------------------
__global__ void __launch_bounds__(256, 2)
k_stage_bc(const float* __restrict__ xv_sum, const float* __restrict__ xq,
           const float* __restrict__ W_t1,
           const float* __restrict__ W_mu1, const float* __restrict__ b_mu1,
           const float* __restrict__ W_lv1, const float* __restrict__ b_lv1,
           const float* __restrict__ W_mu2, const float* __restrict__ b_mu2,
           const float* __restrict__ W_lv2, const float* __restrict__ b_lv2,
           const float* __restrict__ y_hist, const int* __restrict__ label,
           const int* __restrict__ perm, const int* __restrict__ rand_idx,
           const float* __restrict__ b_t1, const float* __restrict__ W_t2,
           const float* __restrict__ b_t2,
           double* __restrict__ dv, double* __restrict__ dq,
           double* __restrict__ club_partial, unsigned int* __restrict__ ctr,
           float* __restrict__ out) {
    // MINE branch LDS
    __shared__ double s_v[4][H_MINE];
    __shared__ double s_q[4][H_MINE];
    // CLUB branch LDS
    __shared__ float  sx[HID];
    __shared__ double s_mu[32][H_CLUB];
    __shared__ double s_lv[32][H_CLUB];
    __shared__ float  s_hmu[H_CLUB];
    __shared__ float  s_hlv[H_CLUB];
    __shared__ int    htab[2048];
    __shared__ int    s_list[1024];
    __shared__ int    s_nlist;
    // shared by reduction + ticket tail
    __shared__ double red[256];
    __shared__ unsigned int s_ticket;

    const int blk = blockIdx.x;
    const int tid = threadIdx.x;

    if (blk < 256) {
        // ---- MINE: block = (b, quarter q). threads = j(64) x kk(4). (R5 code)
        const int b  = blk >> 2;
        const int q  = blk & 3;
        const int j  = tid & 63;
        const int kk = tid >> 6;                       // 0..3
        const float* xvb = xv_sum + (size_t)b * IMG;
        const float* xqb = xq + (size_t)b * HID;

        double a0 = 0, a1 = 0, a2 = 0, a3 = 0;
        {
            const int k0 = q * (IMG / 4) + kk * (IMG / 16);   // 88-wide chunk
            #pragma unroll 2
            for (int t = 0; t < IMG / 16; t += 4) {
                const int k = k0 + t;
                a0 = fma((double)xvb[k],     (double)W_t1[(size_t)(k)     * H_MINE + j], a0);
                a1 = fma((double)xvb[k + 1], (double)W_t1[(size_t)(k + 1) * H_MINE + j], a1);
                a2 = fma((double)xvb[k + 2], (double)W_t1[(size_t)(k + 2) * H_MINE + j], a2);
                a3 = fma((double)xvb[k + 3], (double)W_t1[(size_t)(k + 3) * H_MINE + j], a3);
            }
        }
        s_v[kk][j] = (a0 + a1) + (a2 + a3);

        double q0 = 0, q1 = 0, q2 = 0, q3 = 0;
        {
            const int k0 = q * (HID / 4) + kk * (HID / 16);   // 48-wide chunk
            #pragma unroll 2
            for (int t = 0; t < HID / 16; t += 4) {
                const int k = k0 + t;
                q0 = fma((double)xqb[k],     (double)W_t1[(size_t)(IMG + k)     * H_MINE + j], q0);
                q1 = fma((double)xqb[k + 1], (double)W_t1[(size_t)(IMG + k + 1) * H_MINE + j], q1);
                q2 = fma((double)xqb[k + 2], (double)W_t1[(size_t)(IMG + k + 2) * H_MINE + j], q2);
                q3 = fma((double)xqb[k + 3], (double)W_t1[(size_t)(IMG + k + 3) * H_MINE + j], q3);
            }
        }
        s_q[kk][j] = (q0 + q1) + (q2 + q3);
        __syncthreads();
        if (tid < H_MINE) {
            double sv = (s_v[0][tid] + s_v[1][tid]) + (s_v[2][tid] + s_v[3][tid]);
            double sq = (s_q[0][tid] + s_q[1][tid]) + (s_q[2][tid] + s_q[3][tid]);
            atomicAdd(&dv[b * H_MINE + tid], sv * (1.0 / (double)S_VIT));
            atomicAdd(&dq[b * H_MINE + tid], sq);
        }
    } else {
        // ---- CLUB: one block per b. Phase 1: hidden layer (bit-identical to
        // round-5/6 stage_b club branch; h stays in LDS).
        const int b  = blk - 256;
        const int pb = perm[b];
        for (int i = tid; i < HID; i += 256) sx[i] = xq[(size_t)b * HID + i];
        __syncthreads();
        {
            const int h4 = (tid & 7) * 4;
            const int kk = tid >> 3;                   // 0..31
            const int k0 = kk * 24;
            double m0 = 0, m1 = 0, m2 = 0, m3 = 0;
            double l0 = 0, l1 = 0, l2 = 0, l3 = 0;
            #pragma unroll 4
            for (int t = 0; t < 24; ++t) {
                const int k = k0 + t;
                const float4 wm = *(const float4*)&W_mu1[(size_t)k * H_CLUB + h4];
                const float4 wl = *(const float4*)&W_lv1[(size_t)k * H_CLUB + h4];
                const double xv = (double)sx[k];
                m0 = fma(xv, (double)wm.x, m0);
                m1 = fma(xv, (double)wm.y, m1);
                m2 = fma(xv, (double)wm.z, m2);
                m3 = fma(xv, (double)wm.w, m3);
                l0 = fma(xv, (double)wl.x, l0);
                l1 = fma(xv, (double)wl.y, l1);
                l2 = fma(xv, (double)wl.z, l2);
                l3 = fma(xv, (double)wl.w, l3);
            }
            s_mu[kk][h4 + 0] = m0; s_mu[kk][h4 + 1] = m1;
            s_mu[kk][h4 + 2] = m2; s_mu[kk][h4 + 3] = m3;
            s_lv[kk][h4 + 0] = l0; s_lv[kk][h4 + 1] = l1;
            s_lv[kk][h4 + 2] = l2; s_lv[kk][h4 + 3] = l3;
        }
        // hash init (overlap-safe: different LDS arrays)
        for (int i = tid; i < 2048; i += 256) htab[i] = -1;
        if (tid == 0) s_nlist = 0;
        __syncthreads();
        if (tid < H_CLUB) {
            double am = (double)b_mu1[tid], al = (double)b_lv1[tid];
            #pragma unroll
            for (int i = 0; i < 32; ++i) { am += s_mu[i][tid]; al += s_lv[i][tid]; }
            s_hmu[tid] = fmaxf((float)am, 0.f);
            s_hlv[tid] = fmaxf((float)al, 0.f);
        }
        // Phase 2: dedup candidate c's from labels[b] and labels[pb]
        for (int i = tid; i < 2 * L; i += 256) {
            int raw = (i < L) ? label[(size_t)b * L + i] : label[(size_t)pb * L + (i - L)];
            int c = (raw == -100) ? 0 : raw;
            int slot = c & 2047;
            while (true) {
                int prev = atomicCAS(&htab[slot], -1, c);
                if (prev == -1) { int p = atomicAdd(&s_nlist, 1); s_list[p] = c; break; }
                if (prev == c) break;
                slot = (slot + 1) & 2047;
            }
        }
        __syncthreads();
        // Phase 3: evaluate the FROZEN per-term fp32 expression at distinct c's
        const int nl = s_nlist;
        double total = 0.0;
        for (int i = tid; i < nl; i += 256) {
            const int c = s_list[i];
            float wm[H_CLUB], wl[H_CLUB];
            #pragma unroll
            for (int h = 0; h < H_CLUB; ++h) {
                wm[h] = W_mu2[(size_t)h * C + c];
                wl[h] = W_lv2[(size_t)h * C + c];
            }
            float mu = b_mu2[c], lv = b_lv2[c];
            #pragma unroll
            for (int h = 0; h < H_CLUB; ++h) {
                mu = fmaf(s_hmu[h], wm[h], mu);
                lv = fmaf(s_hlv[h], wl[h], lv);
            }
            const float th = tanhf(lv);
            const float iv = 1.0f / (expf(th) + 1e-6f);
            const float y  = y_hist[(size_t)b  * C + c] * (1.0f / (float)L);
            const float yp = y_hist[(size_t)pb * C + c] * (1.0f / (float)L);
            const float dn = mu - yp;
            const float dp = mu - y;
            total += (double)(iv * (dn * dn - dp * dp));
        }
        red[tid] = total;
        __syncthreads();
        for (int off = 128; off > 0; off >>= 1) {
            if (tid < off) red[tid] += red[tid + off];
            __syncthreads();
        }
        if (tid == 0) club_partial[b] = red[0];
    }

    // ---- ticket: last-finishing block runs the final combine (R6 pattern)
    __syncthreads();
    if (tid == 0) {
        __threadfence();                       // release: partials/dv/dq visible
        s_ticket = atomicAdd(ctr, 1u);
    }
    __syncthreads();
    if (s_ticket != N_BC_BLOCKS - 1) return;
    __threadfence();                           // acquire

    double cp = 0.0;
    for (int i = tid; i < B; i += 256) cp += club_partial[i];
    red[tid] = cp;
    __syncthreads();
    for (int off = 128; off > 0; off >>= 1) {
        if (tid < off) red[tid] += red[tid + off];
        __syncthreads();
    }
    const double club_total = red[0];

    if (tid < B) {  // wave 0 only (B == 64 == wavefront size)
        const int b  = tid;
        const int rb = rand_idx[b];
        double a0 = 0.0, a1 = 0.0;
        #pragma unroll 4
        for (int j = 0; j < H_MINE; ++j) {
            const double base_v = dv[b * H_MINE + j] + (double)b_t1[j];
            const double v0 = base_v + dq[b * H_MINE + j];
            const double v1 = base_v + dq[rb * H_MINE + j];
            const double w = (double)W_t2[j];
            a0 = fma(fmax(v0, 0.0), w, a0);
            a1 = fma(fmax(v1, 0.0), w, a1);
        }
        const double T0 = a0 + (double)b_t2[0];
        const double T1 = a1 + (double)b_t2[0];

        double msum = T0;
        #pragma unroll
        for (int off = 32; off > 0; off >>= 1) msum += __shfl_down(msum, off, 64);
        double mx = T1;
        #pragma unroll
        for (int off = 32; off > 0; off >>= 1) mx = fmax(mx, __shfl_down(mx, off, 64));
        mx = __shfl(mx, 0, 64);
        double e = exp(T1 - mx);
        #pragma unroll
        for (int off = 32; off > 0; off >>= 1) e += __shfl_down(e, off, 64);

        if (tid == 0) {
            const double mean0 = msum * (1.0 / (double)B);
            const double lse   = mx + log(e);
            const double I_xz  = mean0 - (lse - log((double)B));
            const double I_zy  = club_total / (2.0 * (double)B);
            out[0] = (float)(I_zy - 0.1 * I_xz);
        }
    }
}

// ---------------------------------------------------------------------------
extern "C" void kernel_launch(void* const* d_in, const int* in_sizes, int n_in,
                              void* d_out, int out_size, void* d_ws, size_t ws_size,
                              hipStream_t stream) {
    const float* vit     = (const float*)d_in[0];
    const float* qformer = (const float*)d_in[1];
    const int*   label   = (const int*)d_in[2];
    const int*   perm    = (const int*)d_in[3];
    const int*   randi   = (const int*)d_in[4];
    const float* W_mu1   = (const float*)d_in[5];
    const float* b_mu1   = (const float*)d_in[6];
    const float* W_mu2   = (const float*)d_in[7];
    const float* b_mu2   = (const float*)d_in[8];
    const float* W_lv1   = (const float*)d_in[9];
    const float* b_lv1   = (const float*)d_in[10];
    const float* W_lv2   = (const float*)d_in[11];
    const float* b_lv2   = (const float*)d_in[12];
    const float* W_t1    = (const float*)d_in[13];
    const float* b_t1    = (const float*)d_in[14];
    const float* W_t2    = (const float*)d_in[15];
    const float* b_t2    = (const float*)d_in[16];

    float* ws      = (float*)d_ws;
    float* xv_sum  = ws + OFF_XVSUM;
    float* y_hist  = ws + OFF_YHIST;
    double* dv64   = (double*)(ws + OFF_DV64);
    double* dq64   = (double*)(ws + OFF_DQ64);
    unsigned int* ctr = (unsigned int*)(ws + OFF_CTR);
    float* xq      = ws + OFF_XQ;
    double* club_p = (double*)(ws + OFF_CLUBP);

    // Zero the accumulation buffers (xv_sum, y_hist, dv64, dq64, ctr).
    hipMemsetAsync(ws, 0, (size_t)WS_ZERO_FLOATS * sizeof(float), stream);

    k_stage_a<<<1080, 256, 0, stream>>>(vit, qformer, label, xv_sum, xq, y_hist);
    k_stage_bc<<<N_BC_BLOCKS, 256, 0, stream>>>(
        xv_sum, xq, W_t1, W_mu1, b_mu1, W_lv1, b_lv1,
        W_mu2, b_mu2, W_lv2, b_lv2, y_hist, label, perm, randi,
        b_t1, W_t2, b_t2, dv64, dq64, club_p, ctr, (float*)d_out);
}

// Round 8
// 231.917 us; speedup vs baseline: 1.3456x; 1.3456x over previous
//
#include <hip/hip_runtime.h>
#include <hip/hip_bf16.h>
#include <math.h>

// Problem constants (from reference)
#define B       64
#define S_VIT   257
#define S_Q     32
#define L       512
#define IMG     1408
#define HID     768
#define C       30000
#define H_CLUB  32
#define H_MINE  64

// ---------------------------------------------------------------------------
// ROUND LOG (dur_us / absmax):
//  R3 455 / 2.98e-8 PASS  six kernels, latency-bound mine_dot+club_hidden
//  R4 303  fixed mine_dot; k_final serial-exp 88us, club_hidden VGPR-starved 69us
//  R5 221  stage merge + wave-parallel final  <-- BEST
//  R6 229  + ticket fusion + float4 LDS (noise-level regression)
//  R7 312  sparse CLUB gather -> 122MB scattered W2 over-fetch. REVERTED.
//  R8 = R5 structure + 16-split vit mean + float4 LDS h-reads in club_main.
// Precision ledger (absmax == 2.980232e-08 == 1 ulp of out, threshold 1.08 ulp):
//  - per-(b,c) fp32 CLUB term expression FROZEN since round 3.
//  - fp64 summation ORDER free (R4->R7 reorders left absmax bit-identical).
//  - xv_sum fp32 atomicAdd order nondeterministic by construction -> safe.
// ---------------------------------------------------------------------------
#define OFF_XVSUM   0
#define OFF_YHIST   (OFF_XVSUM + B * IMG)            // 90112
#define OFF_DV64    (OFF_YHIST + B * C)              // 2010112 (8B aligned)
#define OFF_DQ64    (OFF_DV64 + 2 * B * H_MINE)      // 2018304
#define WS_ZERO_FLOATS (OFF_DQ64 + 2 * B * H_MINE)   // 2026496
#define OFF_XQ      WS_ZERO_FLOATS                   // 2026496
#define OFF_HMU     (OFF_XQ + B * HID)               // 2075648
#define OFF_HLV     (OFF_HMU + B * H_CLUB)           // 2077696
#define OFF_CLUBP   (OFF_HLV + B * H_CLUB)           // 2079744 (8B aligned)
#define N_CLUB_BLK_X 118
#define N_CLUB_BLK_Y 4
#define N_CLUB_PART (N_CLUB_BLK_X * N_CLUB_BLK_Y)    // 472

// ---------------------------------------------------------------------------
// Stage A: vit mean 16 splits (blocks 0..1023) + xq mean float4 (1024..1071)
//          + label histogram (1072..1079).
// ---------------------------------------------------------------------------
__global__ void k_stage_a(const float* __restrict__ vit, const float* __restrict__ qf,
                          const int* __restrict__ label,
                          float* __restrict__ xv_sum, float* __restrict__ xq,
                          float* __restrict__ y_hist) {
    const int blk = blockIdx.x;
    const int tid = threadIdx.x;
    if (blk < 1024) {
        const int b     = blk >> 4;
        const int split = blk & 15;
        const int s0 = (split * S_VIT) >> 4;
        const int s1 = ((split + 1) * S_VIT) >> 4;
        const float4* row = (const float4*)(vit + (size_t)b * S_VIT * IMG);
        float4 a0 = make_float4(0.f, 0.f, 0.f, 0.f);
        float4 a1 = make_float4(0.f, 0.f, 0.f, 0.f);
        const bool second = (tid < 96);  // 352 float4 columns; 256 + 96
        for (int s = s0; s < s1; ++s) {
            const float4* p = row + (size_t)s * (IMG / 4);
            float4 v = p[tid];
            a0.x += v.x; a0.y += v.y; a0.z += v.z; a0.w += v.w;
            if (second) {
                float4 w = p[tid + 256];
                a1.x += w.x; a1.y += w.y; a1.z += w.z; a1.w += w.w;
            }
        }
        float* out = xv_sum + (size_t)b * IMG;
        atomicAdd(&out[tid * 4 + 0], a0.x);
        atomicAdd(&out[tid * 4 + 1], a0.y);
        atomicAdd(&out[tid * 4 + 2], a0.z);
        atomicAdd(&out[tid * 4 + 3], a0.w);
        if (second) {
            atomicAdd(&out[(tid + 256) * 4 + 0], a1.x);
            atomicAdd(&out[(tid + 256) * 4 + 1], a1.y);
            atomicAdd(&out[(tid + 256) * 4 + 2], a1.z);
            atomicAdd(&out[(tid + 256) * 4 + 3], a1.w);
        }
    } else if (blk < 1072) {
        const int idx = (blk - 1024) * 256 + tid;      // < B*HID/4
        const int b  = idx / (HID / 4);
        const int k4 = idx % (HID / 4);
        const float* base = qf + (size_t)b * S_Q * HID + k4 * 4;
        float4 s = make_float4(0.f, 0.f, 0.f, 0.f);
        #pragma unroll
        for (int t = 0; t < S_Q; ++t) {
            const float4 v = *(const float4*)(base + (size_t)t * HID);
            s.x += v.x; s.y += v.y; s.z += v.z; s.w += v.w;
        }
        const float inv = 1.0f / (float)S_Q;
        s.x *= inv; s.y *= inv; s.z *= inv; s.w *= inv;
        ((float4*)xq)[(size_t)b * (HID / 4) + k4] = s;
    } else {
        const int idx = (blk - 1072) * 256 + tid;      // 0..2047
        for (int t = idx; t < B * L; t += 2048) {
            int lab = label[t];
            if (lab == -100) lab = 0;
            const int b = t >> 9;                      // t / L
            atomicAdd(&y_hist[(size_t)b * C + lab], 1.0f);
        }
    }
}

// ---------------------------------------------------------------------------
// Stage B: MINE first-layer dots (blocks 0..255) + CLUB hidden (256..319).
// (R5 verbatim — measured best.)
// ---------------------------------------------------------------------------
__global__ void __launch_bounds__(256, 2)
k_stage_b(const float* __restrict__ xv_sum, const float* __restrict__ xq,
          const float* __restrict__ W_t1,
          const float* __restrict__ W_mu1, const float* __restrict__ b_mu1,
          const float* __restrict__ W_lv1, const float* __restrict__ b_lv1,
          double* __restrict__ dv, double* __restrict__ dq,
          float* __restrict__ h_mu, float* __restrict__ h_lv) {
    const int blk = blockIdx.x;
    const int tid = threadIdx.x;
    if (blk < 256) {
        __shared__ double s_v[4][H_MINE];
        __shared__ double s_q[4][H_MINE];
        const int b  = blk >> 2;
        const int q  = blk & 3;
        const int j  = tid & 63;
        const int kk = tid >> 6;                       // 0..3
        const float* xvb = xv_sum + (size_t)b * IMG;
        const float* xqb = xq + (size_t)b * HID;

        double a0 = 0, a1 = 0, a2 = 0, a3 = 0;
        {
            const int k0 = q * (IMG / 4) + kk * (IMG / 16);   // 88-wide chunk
            #pragma unroll 2
            for (int t = 0; t < IMG / 16; t += 4) {
                const int k = k0 + t;
                a0 = fma((double)xvb[k],     (double)W_t1[(size_t)(k)     * H_MINE + j], a0);
                a1 = fma((double)xvb[k + 1], (double)W_t1[(size_t)(k + 1) * H_MINE + j], a1);
                a2 = fma((double)xvb[k + 2], (double)W_t1[(size_t)(k + 2) * H_MINE + j], a2);
                a3 = fma((double)xvb[k + 3], (double)W_t1[(size_t)(k + 3) * H_MINE + j], a3);
            }
        }
        s_v[kk][j] = (a0 + a1) + (a2 + a3);

        double q0 = 0, q1 = 0, q2 = 0, q3 = 0;
        {
            const int k0 = q * (HID / 4) + kk * (HID / 16);   // 48-wide chunk
            #pragma unroll 2
            for (int t = 0; t < HID / 16; t += 4) {
                const int k = k0 + t;
                q0 = fma((double)xqb[k],     (double)W_t1[(size_t)(IMG + k)     * H_MINE + j], q0);
                q1 = fma((double)xqb[k + 1], (double)W_t1[(size_t)(IMG + k + 1) * H_MINE + j], q1);
                q2 = fma((double)xqb[k + 2], (double)W_t1[(size_t)(IMG + k + 2) * H_MINE + j], q2);
                q3 = fma((double)xqb[k + 3], (double)W_t1[(size_t)(IMG + k + 3) * H_MINE + j], q3);
            }
        }
        s_q[kk][j] = (q0 + q1) + (q2 + q3);
        __syncthreads();
        if (tid < H_MINE) {
            double sv = (s_v[0][tid] + s_v[1][tid]) + (s_v[2][tid] + s_v[3][tid]);
            double sq = (s_q[0][tid] + s_q[1][tid]) + (s_q[2][tid] + s_q[3][tid]);
            atomicAdd(&dv[b * H_MINE + tid], sv * (1.0 / (double)S_VIT));
            atomicAdd(&dq[b * H_MINE + tid], sq);
        }
    } else {
        __shared__ float  sx[HID];
        __shared__ double s_mu[32][H_CLUB];
        __shared__ double s_lv[32][H_CLUB];
        const int b = blk - 256;
        for (int i = tid; i < HID; i += 256) sx[i] = xq[(size_t)b * HID + i];
        __syncthreads();
        const int h4 = (tid & 7) * 4;
        const int kk = tid >> 3;                       // 0..31
        const int k0 = kk * 24;
        double m0 = 0, m1 = 0, m2 = 0, m3 = 0;
        double l0 = 0, l1 = 0, l2 = 0, l3 = 0;
        #pragma unroll 4
        for (int t = 0; t < 24; ++t) {
            const int k = k0 + t;
            const float4 wm = *(const float4*)&W_mu1[(size_t)k * H_CLUB + h4];
            const float4 wl = *(const float4*)&W_lv1[(size_t)k * H_CLUB + h4];
            const double xv = (double)sx[k];
            m0 = fma(xv, (double)wm.x, m0);
            m1 = fma(xv, (double)wm.y, m1);
            m2 = fma(xv, (double)wm.z, m2);
            m3 = fma(xv, (double)wm.w, m3);
            l0 = fma(xv, (double)wl.x, l0);
            l1 = fma(xv, (double)wl.y, l1);
            l2 = fma(xv, (double)wl.z, l2);
            l3 = fma(xv, (double)wl.w, l3);
        }
        s_mu[kk][h4 + 0] = m0; s_mu[kk][h4 + 1] = m1;
        s_mu[kk][h4 + 2] = m2; s_mu[kk][h4 + 3] = m3;
        s_lv[kk][h4 + 0] = l0; s_lv[kk][h4 + 1] = l1;
        s_lv[kk][h4 + 2] = l2; s_lv[kk][h4 + 3] = l3;
        __syncthreads();
        if (tid < H_CLUB) {
            double am = (double)b_mu1[tid], al = (double)b_lv1[tid];
            #pragma unroll
            for (int i = 0; i < 32; ++i) { am += s_mu[i][tid]; al += s_lv[i][tid]; }
            h_mu[b * H_CLUB + tid] = fmaxf((float)am, 0.f);
            h_lv[b * H_CLUB + tid] = fmaxf((float)al, 0.f);
        }
    }
}

// ---------------------------------------------------------------------------
// K4: dense CLUB main (R5 structure; float4 LDS h-reads — bit-identical fmaf
// order, 4x fewer LDS issues). W2 read is coalesced streaming along c.
// ---------------------------------------------------------------------------
__global__ void k_club_main(const float* __restrict__ W_mu2, const float* __restrict__ b_mu2,
                            const float* __restrict__ W_lv2, const float* __restrict__ b_lv2,
                            const float* __restrict__ h_mu, const float* __restrict__ h_lv,
                            const float* __restrict__ y_hist, const int* __restrict__ perm,
                            double* __restrict__ club_partial) {
    __shared__ __align__(16) float s_hmu[16 * H_CLUB];
    __shared__ __align__(16) float s_hlv[16 * H_CLUB];
    __shared__ int   s_perm[16];
    __shared__ double red[256];
    const int tid = threadIdx.x;
    const int c   = blockIdx.x * 256 + tid;
    const int b0  = blockIdx.y * 16;
    if (tid < 16) s_perm[tid] = perm[b0 + tid];
    for (int i = tid; i < 16 * H_CLUB; i += 256) {
        s_hmu[i] = h_mu[b0 * H_CLUB + i];
        s_hlv[i] = h_lv[b0 * H_CLUB + i];
    }
    __syncthreads();

    double total = 0.0;
    if (c < C) {
        float wm[H_CLUB], wl[H_CLUB];
        #pragma unroll
        for (int h = 0; h < H_CLUB; ++h) {
            wm[h] = W_mu2[(size_t)h * C + c];
            wl[h] = W_lv2[(size_t)h * C + c];
        }
        const float bm = b_mu2[c], bl = b_lv2[c];
        for (int bb = 0; bb < 16; ++bb) {
            const float4* hm4 = (const float4*)&s_hmu[bb * H_CLUB];
            const float4* hl4 = (const float4*)&s_hlv[bb * H_CLUB];
            float mu = bm, lv = bl;
            #pragma unroll
            for (int h8 = 0; h8 < 8; ++h8) {
                const float4 hm = hm4[h8];
                const float4 hl = hl4[h8];
                const int h = h8 * 4;
                mu = fmaf(hm.x, wm[h + 0], mu);
                mu = fmaf(hm.y, wm[h + 1], mu);
                mu = fmaf(hm.z, wm[h + 2], mu);
                mu = fmaf(hm.w, wm[h + 3], mu);
                lv = fmaf(hl.x, wl[h + 0], lv);
                lv = fmaf(hl.y, wl[h + 1], lv);
                lv = fmaf(hl.z, wl[h + 2], lv);
                lv = fmaf(hl.w, wl[h + 3], lv);
            }
            const float th = tanhf(lv);
            const float iv = 1.0f / (expf(th) + 1e-6f);
            const int b = b0 + bb;
            const float y  = y_hist[(size_t)b * C + c] * (1.0f / (float)L);
            const float yp = y_hist[(size_t)s_perm[bb] * C + c] * (1.0f / (float)L);
            const float dn = mu - yp;
            const float dp = mu - y;
            total += (double)(iv * (dn * dn - dp * dp));
        }
    }
    red[tid] = total;
    __syncthreads();
    for (int off = 128; off > 0; off >>= 1) {
        if (tid < off) red[tid] += red[tid + off];
        __syncthreads();
    }
    if (tid == 0) club_partial[blockIdx.y * gridDim.x + blockIdx.x] = red[0];
}

// ---------------------------------------------------------------------------
// K6: final (R5 verbatim). Wave-0 parallel T/logsumexp, fp64 throughout.
// ---------------------------------------------------------------------------
__global__ void k_final(const double* __restrict__ dv, const double* __restrict__ dq,
                        const float* __restrict__ b_t1, const float* __restrict__ W_t2,
                        const float* __restrict__ b_t2, const int* __restrict__ rand_idx,
                        const double* __restrict__ club_partial,
                        float* __restrict__ out) {
    __shared__ double red[256];
    const int tid = threadIdx.x;
    double cp = 0.0;
    for (int i = tid; i < N_CLUB_PART; i += 256) cp += club_partial[i];
    red[tid] = cp;
    __syncthreads();
    for (int off = 128; off > 0; off >>= 1) {
        if (tid < off) red[tid] += red[tid + off];
        __syncthreads();
    }
    const double club_total = red[0];

    if (tid < B) {  // wave 0 only (B == 64 == wavefront size)
        const int b  = tid;
        const int rb = rand_idx[b];
        double a0 = 0.0, a1 = 0.0;
        #pragma unroll 4
        for (int j = 0; j < H_MINE; ++j) {
            const double base_v = dv[b * H_MINE + j] + (double)b_t1[j];
            const double v0 = base_v + dq[b * H_MINE + j];
            const double v1 = base_v + dq[rb * H_MINE + j];
            const double w = (double)W_t2[j];
            a0 = fma(fmax(v0, 0.0), w, a0);
            a1 = fma(fmax(v1, 0.0), w, a1);
        }
        const double T0 = a0 + (double)b_t2[0];
        const double T1 = a1 + (double)b_t2[0];

        double msum = T0;
        #pragma unroll
        for (int off = 32; off > 0; off >>= 1) msum += __shfl_down(msum, off, 64);
        double mx = T1;
        #pragma unroll
        for (int off = 32; off > 0; off >>= 1) mx = fmax(mx, __shfl_down(mx, off, 64));
        mx = __shfl(mx, 0, 64);
        double e = exp(T1 - mx);
        #pragma unroll
        for (int off = 32; off > 0; off >>= 1) e += __shfl_down(e, off, 64);

        if (tid == 0) {
            const double mean0 = msum * (1.0 / (double)B);
            const double lse   = mx + log(e);
            const double I_xz  = mean0 - (lse - log((double)B));
            const double I_zy  = club_total / (2.0 * (double)B);
            out[0] = (float)(I_zy - 0.1 * I_xz);
        }
    }
}

// ---------------------------------------------------------------------------
extern "C" void kernel_launch(void* const* d_in, const int* in_sizes, int n_in,
                              void* d_out, int out_size, void* d_ws, size_t ws_size,
                              hipStream_t stream) {
    const float* vit     = (const float*)d_in[0];
    const float* qformer = (const float*)d_in[1];
    const int*   label   = (const int*)d_in[2];
    const int*   perm    = (const int*)d_in[3];
    const int*   randi   = (const int*)d_in[4];
    const float* W_mu1   = (const float*)d_in[5];
    const float* b_mu1   = (const float*)d_in[6];
    const float* W_mu2   = (const float*)d_in[7];
    const float* b_mu2   = (const float*)d_in[8];
    const float* W_lv1   = (const float*)d_in[9];
    const float* b_lv1   = (const float*)d_in[10];
    const float* W_lv2   = (const float*)d_in[11];
    const float* b_lv2   = (const float*)d_in[12];
    const float* W_t1    = (const float*)d_in[13];
    const float* b_t1    = (const float*)d_in[14];
    const float* W_t2    = (const float*)d_in[15];
    const float* b_t2    = (const float*)d_in[16];

    float* ws      = (float*)d_ws;
    float* xv_sum  = ws + OFF_XVSUM;
    float* y_hist  = ws + OFF_YHIST;
    double* dv64   = (double*)(ws + OFF_DV64);
    double* dq64   = (double*)(ws + OFF_DQ64);
    float* xq      = ws + OFF_XQ;
    float* h_mu    = ws + OFF_HMU;
    float* h_lv    = ws + OFF_HLV;
    double* club_p = (double*)(ws + OFF_CLUBP);

    // Zero the accumulation buffers (xv_sum, y_hist, dv64, dq64).
    hipMemsetAsync(ws, 0, (size_t)WS_ZERO_FLOATS * sizeof(float), stream);

    k_stage_a<<<1080, 256, 0, stream>>>(vit, qformer, label, xv_sum, xq, y_hist);
    k_stage_b<<<320, 256, 0, stream>>>(xv_sum, xq, W_t1, W_mu1, b_mu1, W_lv1, b_lv1,
                                       dv64, dq64, h_mu, h_lv);
    k_club_main<<<dim3(N_CLUB_BLK_X, N_CLUB_BLK_Y), 256, 0, stream>>>(
        W_mu2, b_mu2, W_lv2, b_lv2, h_mu, h_lv, y_hist, perm, club_p);
    k_final<<<1, 256, 0, stream>>>(dv64, dq64, b_t1, W_t2, b_t2, randi, club_p, (float*)d_out);
}

// Round 9
// 221.917 us; speedup vs baseline: 1.4062x; 1.0451x over previous
//
#include <hip/hip_runtime.h>
#include <hip/hip_bf16.h>
#include <math.h>

// Problem constants (from reference)
#define B       64
#define S_VIT   257
#define S_Q     32
#define L       512
#define IMG     1408
#define HID     768
#define C       30000
#define H_CLUB  32
#define H_MINE  64

// ---------------------------------------------------------------------------
// ROUND LOG (dur_us / absmax 2.980232e-08 PASS unless noted):
//  R3 455  six kernels; latency-bound mine_dot+club_hidden
//  R4 303  fixed mine_dot; final serial-exp 88us, club_hidden VGPR-starved 69us
//  R5 221  stage merge + wave-parallel final  <-- BEST baseline
//  R6 229  ticket fusion + club_main float4 LDS (regressed, reverted)
//  R7 312  sparse CLUB gather -> scattered W2 over-fetch (reverted)
//  R8 232  16-split vit + club_main float4 LDS; PROFILE: stage_a 58.5us at
//          1.26 TB/s, VGPR=32, VALUBusy 0.9% -> MLP-starved vit loop.
//  R9 = R5 verbatim EXCEPT vit-mean unrolled x4 (8 indep loads in flight).
// Precision ledger (absmax == 1 ulp of out, threshold 1.08 ulp):
//  - per-(b,c) fp32 CLUB term expression FROZEN since round 3.
//  - fp64 summation ORDER free (R4->R8 reorders left absmax bit-identical).
//  - xv_sum fp32 atomicAdd order nondeterministic by construction -> s-sum
//    reassociation safe (verified across R5/R8 grouping changes).
// ---------------------------------------------------------------------------
#define OFF_XVSUM   0
#define OFF_YHIST   (OFF_XVSUM + B * IMG)            // 90112
#define OFF_DV64    (OFF_YHIST + B * C)              // 2010112 (8B aligned)
#define OFF_DQ64    (OFF_DV64 + 2 * B * H_MINE)      // 2018304
#define WS_ZERO_FLOATS (OFF_DQ64 + 2 * B * H_MINE)   // 2026496
#define OFF_XQ      WS_ZERO_FLOATS                   // 2026496
#define OFF_HMU     (OFF_XQ + B * HID)               // 2075648
#define OFF_HLV     (OFF_HMU + B * H_CLUB)           // 2077696
#define OFF_CLUBP   (OFF_HLV + B * H_CLUB)           // 2079744 (8B aligned)
#define N_CLUB_BLK_X 118
#define N_CLUB_BLK_Y 4
#define N_CLUB_PART (N_CLUB_BLK_X * N_CLUB_BLK_Y)    // 472

// ---------------------------------------------------------------------------
// Stage A: vit mean 8 splits (blocks 0..511) + xq mean float4 (512..559)
//          + label histogram (560..567).
// vit loop unrolled x4: 4 (or 8 incl. second set) independent float4 loads
// issued before any accumulate -> MLP ~8/thread instead of ~2 (R8 fix).
// ---------------------------------------------------------------------------
__global__ void k_stage_a(const float* __restrict__ vit, const float* __restrict__ qf,
                          const int* __restrict__ label,
                          float* __restrict__ xv_sum, float* __restrict__ xq,
                          float* __restrict__ y_hist) {
    const int blk = blockIdx.x;
    const int tid = threadIdx.x;
    if (blk < 512) {
        const int b     = blk >> 3;
        const int split = blk & 7;
        const int s0 = split * 33;
        const int s1 = (s0 + 33 < S_VIT) ? s0 + 33 : S_VIT;
        const float4* row = (const float4*)(vit + (size_t)b * S_VIT * IMG);
        float4 a0 = make_float4(0.f, 0.f, 0.f, 0.f);
        float4 a1 = make_float4(0.f, 0.f, 0.f, 0.f);
        const bool second = (tid < 96);  // 352 float4 columns; 256 + 96
        int s = s0;
        for (; s + 4 <= s1; s += 4) {
            const float4* p0 = row + (size_t)(s + 0) * (IMG / 4);
            const float4* p1 = row + (size_t)(s + 1) * (IMG / 4);
            const float4* p2 = row + (size_t)(s + 2) * (IMG / 4);
            const float4* p3 = row + (size_t)(s + 3) * (IMG / 4);
            const float4 v0 = p0[tid];
            const float4 v1 = p1[tid];
            const float4 v2 = p2[tid];
            const float4 v3 = p3[tid];
            if (second) {
                const float4 w0 = p0[tid + 256];
                const float4 w1 = p1[tid + 256];
                const float4 w2 = p2[tid + 256];
                const float4 w3 = p3[tid + 256];
                a1.x += (w0.x + w1.x) + (w2.x + w3.x);
                a1.y += (w0.y + w1.y) + (w2.y + w3.y);
                a1.z += (w0.z + w1.z) + (w2.z + w3.z);
                a1.w += (w0.w + w1.w) + (w2.w + w3.w);
            }
            a0.x += (v0.x + v1.x) + (v2.x + v3.x);
            a0.y += (v0.y + v1.y) + (v2.y + v3.y);
            a0.z += (v0.z + v1.z) + (v2.z + v3.z);
            a0.w += (v0.w + v1.w) + (v2.w + v3.w);
        }
        for (; s < s1; ++s) {
            const float4* p = row + (size_t)s * (IMG / 4);
            const float4 v = p[tid];
            a0.x += v.x; a0.y += v.y; a0.z += v.z; a0.w += v.w;
            if (second) {
                const float4 w = p[tid + 256];
                a1.x += w.x; a1.y += w.y; a1.z += w.z; a1.w += w.w;
            }
        }
        float* out = xv_sum + (size_t)b * IMG;
        atomicAdd(&out[tid * 4 + 0], a0.x);
        atomicAdd(&out[tid * 4 + 1], a0.y);
        atomicAdd(&out[tid * 4 + 2], a0.z);
        atomicAdd(&out[tid * 4 + 3], a0.w);
        if (second) {
            atomicAdd(&out[(tid + 256) * 4 + 0], a1.x);
            atomicAdd(&out[(tid + 256) * 4 + 1], a1.y);
            atomicAdd(&out[(tid + 256) * 4 + 2], a1.z);
            atomicAdd(&out[(tid + 256) * 4 + 3], a1.w);
        }
    } else if (blk < 560) {
        const int idx = (blk - 512) * 256 + tid;       // < B*HID/4
        const int b  = idx / (HID / 4);
        const int k4 = idx % (HID / 4);
        const float* base = qf + (size_t)b * S_Q * HID + k4 * 4;
        float4 s = make_float4(0.f, 0.f, 0.f, 0.f);
        #pragma unroll
        for (int t = 0; t < S_Q; ++t) {
            const float4 v = *(const float4*)(base + (size_t)t * HID);
            s.x += v.x; s.y += v.y; s.z += v.z; s.w += v.w;
        }
        const float inv = 1.0f / (float)S_Q;
        s.x *= inv; s.y *= inv; s.z *= inv; s.w *= inv;
        ((float4*)xq)[(size_t)b * (HID / 4) + k4] = s;
    } else {
        const int idx = (blk - 560) * 256 + tid;       // 0..2047
        for (int t = idx; t < B * L; t += 2048) {
            int lab = label[t];
            if (lab == -100) lab = 0;
            const int b = t >> 9;                      // t / L
            atomicAdd(&y_hist[(size_t)b * C + lab], 1.0f);
        }
    }
}

// ---------------------------------------------------------------------------
// Stage B: MINE first-layer dots (blocks 0..255) + CLUB hidden (256..319).
// (R5 verbatim — measured best.)
// ---------------------------------------------------------------------------
__global__ void __launch_bounds__(256, 2)
k_stage_b(const float* __restrict__ xv_sum, const float* __restrict__ xq,
          const float* __restrict__ W_t1,
          const float* __restrict__ W_mu1, const float* __restrict__ b_mu1,
          const float* __restrict__ W_lv1, const float* __restrict__ b_lv1,
          double* __restrict__ dv, double* __restrict__ dq,
          float* __restrict__ h_mu, float* __restrict__ h_lv) {
    const int blk = blockIdx.x;
    const int tid = threadIdx.x;
    if (blk < 256) {
        __shared__ double s_v[4][H_MINE];
        __shared__ double s_q[4][H_MINE];
        const int b  = blk >> 2;
        const int q  = blk & 3;
        const int j  = tid & 63;
        const int kk = tid >> 6;                       // 0..3
        const float* xvb = xv_sum + (size_t)b * IMG;
        const float* xqb = xq + (size_t)b * HID;

        double a0 = 0, a1 = 0, a2 = 0, a3 = 0;
        {
            const int k0 = q * (IMG / 4) + kk * (IMG / 16);   // 88-wide chunk
            #pragma unroll 2
            for (int t = 0; t < IMG / 16; t += 4) {
                const int k = k0 + t;
                a0 = fma((double)xvb[k],     (double)W_t1[(size_t)(k)     * H_MINE + j], a0);
                a1 = fma((double)xvb[k + 1], (double)W_t1[(size_t)(k + 1) * H_MINE + j], a1);
                a2 = fma((double)xvb[k + 2], (double)W_t1[(size_t)(k + 2) * H_MINE + j], a2);
                a3 = fma((double)xvb[k + 3], (double)W_t1[(size_t)(k + 3) * H_MINE + j], a3);
            }
        }
        s_v[kk][j] = (a0 + a1) + (a2 + a3);

        double q0 = 0, q1 = 0, q2 = 0, q3 = 0;
        {
            const int k0 = q * (HID / 4) + kk * (HID / 16);   // 48-wide chunk
            #pragma unroll 2
            for (int t = 0; t < HID / 16; t += 4) {
                const int k = k0 + t;
                q0 = fma((double)xqb[k],     (double)W_t1[(size_t)(IMG + k)     * H_MINE + j], q0);
                q1 = fma((double)xqb[k + 1], (double)W_t1[(size_t)(IMG + k + 1) * H_MINE + j], q1);
                q2 = fma((double)xqb[k + 2], (double)W_t1[(size_t)(IMG + k + 2) * H_MINE + j], q2);
                q3 = fma((double)xqb[k + 3], (double)W_t1[(size_t)(IMG + k + 3) * H_MINE + j], q3);
            }
        }
        s_q[kk][j] = (q0 + q1) + (q2 + q3);
        __syncthreads();
        if (tid < H_MINE) {
            double sv = (s_v[0][tid] + s_v[1][tid]) + (s_v[2][tid] + s_v[3][tid]);
            double sq = (s_q[0][tid] + s_q[1][tid]) + (s_q[2][tid] + s_q[3][tid]);
            atomicAdd(&dv[b * H_MINE + tid], sv * (1.0 / (double)S_VIT));
            atomicAdd(&dq[b * H_MINE + tid], sq);
        }
    } else {
        __shared__ float  sx[HID];
        __shared__ double s_mu[32][H_CLUB];
        __shared__ double s_lv[32][H_CLUB];
        const int b = blk - 256;
        for (int i = tid; i < HID; i += 256) sx[i] = xq[(size_t)b * HID + i];
        __syncthreads();
        const int h4 = (tid & 7) * 4;
        const int kk = tid >> 3;                       // 0..31
        const int k0 = kk * 24;
        double m0 = 0, m1 = 0, m2 = 0, m3 = 0;
        double l0 = 0, l1 = 0, l2 = 0, l3 = 0;
        #pragma unroll 4
        for (int t = 0; t < 24; ++t) {
            const int k = k0 + t;
            const float4 wm = *(const float4*)&W_mu1[(size_t)k * H_CLUB + h4];
            const float4 wl = *(const float4*)&W_lv1[(size_t)k * H_CLUB + h4];
            const double xv = (double)sx[k];
            m0 = fma(xv, (double)wm.x, m0);
            m1 = fma(xv, (double)wm.y, m1);
            m2 = fma(xv, (double)wm.z, m2);
            m3 = fma(xv, (double)wm.w, m3);
            l0 = fma(xv, (double)wl.x, l0);
            l1 = fma(xv, (double)wl.y, l1);
            l2 = fma(xv, (double)wl.z, l2);
            l3 = fma(xv, (double)wl.w, l3);
        }
        s_mu[kk][h4 + 0] = m0; s_mu[kk][h4 + 1] = m1;
        s_mu[kk][h4 + 2] = m2; s_mu[kk][h4 + 3] = m3;
        s_lv[kk][h4 + 0] = l0; s_lv[kk][h4 + 1] = l1;
        s_lv[kk][h4 + 2] = l2; s_lv[kk][h4 + 3] = l3;
        __syncthreads();
        if (tid < H_CLUB) {
            double am = (double)b_mu1[tid], al = (double)b_lv1[tid];
            #pragma unroll
            for (int i = 0; i < 32; ++i) { am += s_mu[i][tid]; al += s_lv[i][tid]; }
            h_mu[b * H_CLUB + tid] = fmaxf((float)am, 0.f);
            h_lv[b * H_CLUB + tid] = fmaxf((float)al, 0.f);
        }
    }
}

// ---------------------------------------------------------------------------
// K4: dense CLUB main (R5 verbatim — scalar LDS h-reads; the float4 variant
// was the common factor in the R6/R8 regressions, reverted).
// ---------------------------------------------------------------------------
__global__ void k_club_main(const float* __restrict__ W_mu2, const float* __restrict__ b_mu2,
                            const float* __restrict__ W_lv2, const float* __restrict__ b_lv2,
                            const float* __restrict__ h_mu, const float* __restrict__ h_lv,
                            const float* __restrict__ y_hist, const int* __restrict__ perm,
                            double* __restrict__ club_partial) {
    __shared__ float s_hmu[16 * H_CLUB];
    __shared__ float s_hlv[16 * H_CLUB];
    __shared__ int   s_perm[16];
    __shared__ double red[256];
    const int tid = threadIdx.x;
    const int c   = blockIdx.x * 256 + tid;
    const int b0  = blockIdx.y * 16;
    if (tid < 16) s_perm[tid] = perm[b0 + tid];
    for (int i = tid; i < 16 * H_CLUB; i += 256) {
        s_hmu[i] = h_mu[b0 * H_CLUB + i];
        s_hlv[i] = h_lv[b0 * H_CLUB + i];
    }
    __syncthreads();

    double total = 0.0;
    if (c < C) {
        float wm[H_CLUB], wl[H_CLUB];
        #pragma unroll
        for (int h = 0; h < H_CLUB; ++h) {
            wm[h] = W_mu2[(size_t)h * C + c];
            wl[h] = W_lv2[(size_t)h * C + c];
        }
        const float bm = b_mu2[c], bl = b_lv2[c];
        for (int bb = 0; bb < 16; ++bb) {
            float mu = bm, lv = bl;
            #pragma unroll
            for (int h = 0; h < H_CLUB; ++h) {
                mu = fmaf(s_hmu[bb * H_CLUB + h], wm[h], mu);
                lv = fmaf(s_hlv[bb * H_CLUB + h], wl[h], lv);
            }
            const float th = tanhf(lv);
            const float iv = 1.0f / (expf(th) + 1e-6f);
            const int b = b0 + bb;
            const float y  = y_hist[(size_t)b * C + c] * (1.0f / (float)L);
            const float yp = y_hist[(size_t)s_perm[bb] * C + c] * (1.0f / (float)L);
            const float dn = mu - yp;
            const float dp = mu - y;
            total += (double)(iv * (dn * dn - dp * dp));
        }
    }
    red[tid] = total;
    __syncthreads();
    for (int off = 128; off > 0; off >>= 1) {
        if (tid < off) red[tid] += red[tid + off];
        __syncthreads();
    }
    if (tid == 0) club_partial[blockIdx.y * gridDim.x + blockIdx.x] = red[0];
}

// ---------------------------------------------------------------------------
// K6: final (R5 verbatim). Wave-0 parallel T/logsumexp, fp64 throughout.
// ---------------------------------------------------------------------------
__global__ void k_final(const double* __restrict__ dv, const double* __restrict__ dq,
                        const float* __restrict__ b_t1, const float* __restrict__ W_t2,
                        const float* __restrict__ b_t2, const int* __restrict__ rand_idx,
                        const double* __restrict__ club_partial,
                        float* __restrict__ out) {
    __shared__ double red[256];
    const int tid = threadIdx.x;
    double cp = 0.0;
    for (int i = tid; i < N_CLUB_PART; i += 256) cp += club_partial[i];
    red[tid] = cp;
    __syncthreads();
    for (int off = 128; off > 0; off >>= 1) {
        if (tid < off) red[tid] += red[tid + off];
        __syncthreads();
    }
    const double club_total = red[0];

    if (tid < B) {  // wave 0 only (B == 64 == wavefront size)
        const int b  = tid;
        const int rb = rand_idx[b];
        double a0 = 0.0, a1 = 0.0;
        #pragma unroll 4
        for (int j = 0; j < H_MINE; ++j) {
            const double base_v = dv[b * H_MINE + j] + (double)b_t1[j];
            const double v0 = base_v + dq[b * H_MINE + j];
            const double v1 = base_v + dq[rb * H_MINE + j];
            const double w = (double)W_t2[j];
            a0 = fma(fmax(v0, 0.0), w, a0);
            a1 = fma(fmax(v1, 0.0), w, a1);
        }
        const double T0 = a0 + (double)b_t2[0];
        const double T1 = a1 + (double)b_t2[0];

        double msum = T0;
        #pragma unroll
        for (int off = 32; off > 0; off >>= 1) msum += __shfl_down(msum, off, 64);
        double mx = T1;
        #pragma unroll
        for (int off = 32; off > 0; off >>= 1) mx = fmax(mx, __shfl_down(mx, off, 64));
        mx = __shfl(mx, 0, 64);
        double e = exp(T1 - mx);
        #pragma unroll
        for (int off = 32; off > 0; off >>= 1) e += __shfl_down(e, off, 64);

        if (tid == 0) {
            const double mean0 = msum * (1.0 / (double)B);
            const double lse   = mx + log(e);
            const double I_xz  = mean0 - (lse - log((double)B));
            const double I_zy  = club_total / (2.0 * (double)B);
            out[0] = (float)(I_zy - 0.1 * I_xz);
        }
    }
}

// ---------------------------------------------------------------------------
extern "C" void kernel_launch(void* const* d_in, const int* in_sizes, int n_in,
                              void* d_out, int out_size, void* d_ws, size_t ws_size,
                              hipStream_t stream) {
    const float* vit     = (const float*)d_in[0];
    const float* qformer = (const float*)d_in[1];
    const int*   label   = (const int*)d_in[2];
    const int*   perm    = (const int*)d_in[3];
    const int*   randi   = (const int*)d_in[4];
    const float* W_mu1   = (const float*)d_in[5];
    const float* b_mu1   = (const float*)d_in[6];
    const float* W_mu2   = (const float*)d_in[7];
    const float* b_mu2   = (const float*)d_in[8];
    const float* W_lv1   = (const float*)d_in[9];
    const float* b_lv1   = (const float*)d_in[10];
    const float* W_lv2   = (const float*)d_in[11];
    const float* b_lv2   = (const float*)d_in[12];
    const float* W_t1    = (const float*)d_in[13];
    const float* b_t1    = (const float*)d_in[14];
    const float* W_t2    = (const float*)d_in[15];
    const float* b_t2    = (const float*)d_in[16];

    float* ws      = (float*)d_ws;
    float* xv_sum  = ws + OFF_XVSUM;
    float* y_hist  = ws + OFF_YHIST;
    double* dv64   = (double*)(ws + OFF_DV64);
    double* dq64   = (double*)(ws + OFF_DQ64);
    float* xq      = ws + OFF_XQ;
    float* h_mu    = ws + OFF_HMU;
    float* h_lv    = ws + OFF_HLV;
    double* club_p = (double*)(ws + OFF_CLUBP);

    // Zero the accumulation buffers (xv_sum, y_hist, dv64, dq64).
    hipMemsetAsync(ws, 0, (size_t)WS_ZERO_FLOATS * sizeof(float), stream);

    k_stage_a<<<568, 256, 0, stream>>>(vit, qformer, label, xv_sum, xq, y_hist);
    k_stage_b<<<320, 256, 0, stream>>>(xv_sum, xq, W_t1, W_mu1, b_mu1, W_lv1, b_lv1,
                                       dv64, dq64, h_mu, h_lv);
    k_club_main<<<dim3(N_CLUB_BLK_X, N_CLUB_BLK_Y), 256, 0, stream>>>(
        W_mu2, b_mu2, W_lv2, b_lv2, h_mu, h_lv, y_hist, perm, club_p);
    k_final<<<1, 256, 0, stream>>>(dv64, dq64, b_t1, W_t2, b_t2, randi, club_p, (float*)d_out);
}